// Round 1
// baseline (320.697 us; speedup 1.0000x reference)
//
#include <hip/hip_runtime.h>
#include <math.h>

#define CAMS 6
#define CCH 256
#define HH 46
#define WW 80
#define HEADS 8
#define PIP 4
#define PP 4
#define KK 16
#define RADIUS_F 0.12f

// Generic batched transpose: in [B][R][Cc] -> out [B][Cc][R]
__global__ void batched_transpose_k(const float* __restrict__ in, float* __restrict__ out,
                                    int Bb, int R, int Cc) {
    long total = (long)Bb * R * Cc;
    long per = (long)R * Cc;
    for (long idx = (long)blockIdx.x * blockDim.x + threadIdx.x; idx < total;
         idx += (long)gridDim.x * blockDim.x) {
        int b = (int)(idx / per);
        long rem = idx - (long)b * per;
        int r = (int)(rem / Cc);
        int j = (int)(rem - (long)r * Cc);
        out[(long)b * per + (long)j * R + r] = in[idx];
    }
}

// Per-query GEMMs: offsets = tanh(q @ offW^T + offB)*R ; wl = q @ wW^T + wB
template <int NT>
__global__ void qgemm_k(const float* __restrict__ query,
                        const float* __restrict__ offT,  // [256][256] (j, r)
                        const float* __restrict__ offB,
                        const float* __restrict__ wT,    // [256][128] (j, r)
                        const float* __restrict__ wB,
                        float* __restrict__ offsets,     // [N][256]
                        float* __restrict__ wl,          // [N][128]
                        int N) {
    __shared__ float q[NT][CCH];
    int n0 = blockIdx.x * NT;
    int tid = threadIdx.x;
    for (int t = 0; t < NT; t++) {
        int n = n0 + t;
        q[t][tid] = (n < N) ? query[(long)n * CCH + tid] : 0.f;
    }
    __syncthreads();

    // offset rows: r = tid (0..255)
    {
        float acc[NT];
        float b = offB[tid];
#pragma unroll
        for (int t = 0; t < NT; t++) acc[t] = b;
        for (int j = 0; j < CCH; j++) {
            float wv = offT[j * CCH + tid];
#pragma unroll
            for (int t = 0; t < NT; t++) acc[t] = fmaf(q[t][j], wv, acc[t]);
        }
        for (int t = 0; t < NT; t++) {
            int n = n0 + t;
            if (n < N) offsets[(long)n * CCH + tid] = tanhf(acc[t]) * RADIUS_F;
        }
    }
    // attention-logit rows: r = tid (0..127), threads 128..255 idle (wave-uniform)
    if (tid < 128) {
        float acc[NT];
        float b = wB[tid];
#pragma unroll
        for (int t = 0; t < NT; t++) acc[t] = b;
        for (int j = 0; j < CCH; j++) {
            float wv = wT[j * 128 + tid];
#pragma unroll
            for (int t = 0; t < NT; t++) acc[t] = fmaf(q[t][j], wv, acc[t]);
        }
        for (int t = 0; t < NT; t++) {
            int n = n0 + t;
            if (n < N) wl[(long)n * 128 + tid] = acc[t];
        }
    }
}

// Per-query sampling + masked softmax + camera fusion.
// feat_t: [CAMS][HH][WW][CCH] (pixel-major -> coalesced channel reads)
__global__ void sample_fuse_k(const float* __restrict__ feat_t,
                              const float* __restrict__ refp,   // [CAMS][N][PIP][2]
                              const int* __restrict__ bev,      // [CAMS][N][PIP] (0/1)
                              const float* __restrict__ offsets,// [N][256]
                              const float* __restrict__ wl,     // [N][128]
                              float* __restrict__ fused,        // [N][256]
                              int N) {
    int n = blockIdx.x;
    int c = threadIdx.x;        // channel 0..255
    int h = c >> 5;             // head

    __shared__ float ref_s[CAMS * PIP * 2];    // 48
    __shared__ int mask_s[CAMS * PIP];         // 24
    __shared__ float wl_s[HEADS * KK];         // 128
    __shared__ float off_s[CCH];               // 256
    __shared__ float w_s[CAMS * HEADS * KK];   // 768

    if (c < CAMS * PIP * 2) {
        int cam = c >> 3, rem = c & 7;
        ref_s[c] = refp[((long)cam * N + n) * 8 + rem];
    }
    if (c < CAMS * PIP) {
        int cam = c >> 2, pip = c & 3;
        mask_s[c] = bev[((long)cam * N + n) * 4 + pip];
    }
    if (c < 128) wl_s[c] = wl[(long)n * 128 + c];
    off_s[c] = offsets[(long)n * CCH + c];
    __syncthreads();

    // masked softmax per (cam, head): 48 threads each do one row of K=16
    if (c < CAMS * HEADS) {
        int cam = c >> 3, hh = c & 7;
        float mmax = -1e30f;
        int any = 0;
#pragma unroll
        for (int k = 0; k < KK; k++) {
            if (mask_s[cam * PIP + (k >> 2)]) {
                float l = wl_s[hh * KK + k];
                mmax = fmaxf(mmax, l);
                any = 1;
            }
        }
        float e[KK];
        float s = 0.f;
#pragma unroll
        for (int k = 0; k < KK; k++) {
            float v = 0.f;
            if (mask_s[cam * PIP + (k >> 2)]) {
                v = expf(wl_s[hh * KK + k] - mmax);
                s += v;
            }
            e[k] = v;
        }
        float inv = any ? 1.f / s : 0.f;
#pragma unroll
        for (int k = 0; k < KK; k++) w_s[(cam * HEADS + hh) * KK + k] = e[k] * inv;
    }
    __syncthreads();

    float acc = 0.f;
    int count = 0;
    for (int cam = 0; cam < CAMS; cam++) {
        int hv = mask_s[cam * 4] | mask_s[cam * 4 + 1] | mask_s[cam * 4 + 2] | mask_s[cam * 4 + 3];
        if (!hv) continue;   // block-uniform
        count++;
        const float* fcam = feat_t + (long)cam * HH * WW * CCH;
        float cam_acc = 0.f;
        for (int pip = 0; pip < PIP; pip++) {
            if (!mask_s[cam * 4 + pip]) continue;  // block-uniform
            float rx = ref_s[(cam * PIP + pip) * 2 + 0];
            float ry = ref_s[(cam * PIP + pip) * 2 + 1];
#pragma unroll
            for (int p = 0; p < PP; p++) {
                int k = pip * PP + p;
                float wgt = w_s[(cam * HEADS + h) * KK + k];
                float lx = rx + off_s[((h * PIP + pip) * PP + p) * 2 + 0];
                float ly = ry + off_s[((h * PIP + pip) * PP + p) * 2 + 1];
                // grid=(loc*2-1) then unnormalize => pixel = loc*dim - 0.5
                float x = lx * WW - 0.5f;
                float y = ly * HH - 0.5f;
                float x0f = floorf(x), y0f = floorf(y);
                float fx = x - x0f, fy = y - y0f;
                int ix = (int)x0f, iy = (int)y0f;
                bool x0ok = (ix >= 0) & (ix < WW);
                bool x1ok = (ix + 1 >= 0) & (ix + 1 < WW);
                bool y0ok = (iy >= 0) & (iy < HH);
                bool y1ok = (iy + 1 >= 0) & (iy + 1 < HH);
                float v = 0.f;
                if (y0ok) {
                    const float* row = fcam + ((long)iy * WW) * CCH;
                    if (x0ok) v = fmaf((1.f - fx) * (1.f - fy), row[(long)ix * CCH + c], v);
                    if (x1ok) v = fmaf(fx * (1.f - fy), row[(long)(ix + 1) * CCH + c], v);
                }
                if (y1ok) {
                    const float* row = fcam + ((long)(iy + 1) * WW) * CCH;
                    if (x0ok) v = fmaf((1.f - fx) * fy, row[(long)ix * CCH + c], v);
                    if (x1ok) v = fmaf(fx * fy, row[(long)(ix + 1) * CCH + c], v);
                }
                cam_acc = fmaf(wgt, v, cam_acc);
            }
        }
        acc += cam_acc;
    }
    if (count == 0) count = 1;
    fused[(long)n * CCH + c] = acc / (float)count;
}

// out = fused @ out_w^T + out_b
template <int NT>
__global__ void outproj_k(const float* __restrict__ fused,
                          const float* __restrict__ outT,  // [256][256] (j, r)
                          const float* __restrict__ outB,
                          float* __restrict__ out, int N) {
    __shared__ float f[NT][CCH];
    int n0 = blockIdx.x * NT;
    int tid = threadIdx.x;
    for (int t = 0; t < NT; t++) {
        int n = n0 + t;
        f[t][tid] = (n < N) ? fused[(long)n * CCH + tid] : 0.f;
    }
    __syncthreads();
    float acc[NT];
    float b = outB[tid];
#pragma unroll
    for (int t = 0; t < NT; t++) acc[t] = b;
    for (int j = 0; j < CCH; j++) {
        float wv = outT[j * CCH + tid];
#pragma unroll
        for (int t = 0; t < NT; t++) acc[t] = fmaf(f[t][j], wv, acc[t]);
    }
    for (int t = 0; t < NT; t++) {
        int n = n0 + t;
        if (n < N) out[(long)n * CCH + tid] = acc[t];
    }
}

extern "C" void kernel_launch(void* const* d_in, const int* in_sizes, int n_in,
                              void* d_out, int out_size, void* d_ws, size_t ws_size,
                              hipStream_t stream) {
    const float* query    = (const float*)d_in[0];  // [1,N,256]
    const float* imfeat   = (const float*)d_in[1];  // [1,6,256,46,80]
    const float* refp     = (const float*)d_in[2];  // [1,6,N,4,2]
    const int*   bev      = (const int*)d_in[3];    // [1,6,N,4] bool->int32
    const float* offset_w = (const float*)d_in[4];  // [256,256]
    const float* offset_b = (const float*)d_in[5];  // [256]
    const float* weight_w = (const float*)d_in[6];  // [128,256]
    const float* weight_b = (const float*)d_in[7];  // [128]
    const float* out_w    = (const float*)d_in[8];  // [256,256]
    const float* out_b    = (const float*)d_in[9];  // [256]
    float* out = (float*)d_out;

    int N = in_sizes[0] / CCH;  // 2500

    // workspace partition (floats)
    float* ws = (float*)d_ws;
    float* feat_t = ws;                                        // 6*46*80*256
    float* offT   = feat_t + (size_t)CAMS * HH * WW * CCH;     // 256*256
    float* wTw    = offT + (size_t)CCH * CCH;                  // 256*128
    float* outT   = wTw + (size_t)128 * CCH;                   // 256*256
    float* offs   = outT + (size_t)CCH * CCH;                  // N*256
    float* wl     = offs + (size_t)N * CCH;                    // N*128
    float* fusedb = wl + (size_t)N * 128;                      // N*256

    // transposes
    batched_transpose_k<<<2048, 256, 0, stream>>>(imfeat, feat_t, CAMS, CCH, HH * WW);
    batched_transpose_k<<<256, 256, 0, stream>>>(offset_w, offT, 1, CCH, CCH);
    batched_transpose_k<<<128, 256, 0, stream>>>(weight_w, wTw, 1, 128, CCH);
    batched_transpose_k<<<256, 256, 0, stream>>>(out_w, outT, 1, CCH, CCH);

    qgemm_k<8><<<(N + 7) / 8, 256, 0, stream>>>(query, offT, offset_b, wTw, weight_b,
                                                offs, wl, N);
    sample_fuse_k<<<N, 256, 0, stream>>>(feat_t, refp, bev, offs, wl, fusedb, N);
    outproj_k<8><<<(N + 7) / 8, 256, 0, stream>>>(fusedb, outT, out_b, out, N);
}

// Round 3
// 200.727 us; speedup vs baseline: 1.5977x; 1.5977x over previous
//
#include <hip/hip_runtime.h>
#include <math.h>

#define CAMS 6
#define CCH 256
#define HH 46
#define WW 80
#define HEADS 8
#define PIP 4
#define PP 4
#define KK 16
#define RADIUS_F 0.12f

// Generic batched transpose: in [B][R][Cc] -> out [B][Cc][R]
__global__ void batched_transpose_k(const float* __restrict__ in, float* __restrict__ out,
                                    int Bb, int R, int Cc) {
    long total = (long)Bb * R * Cc;
    long per = (long)R * Cc;
    for (long idx = (long)blockIdx.x * blockDim.x + threadIdx.x; idx < total;
         idx += (long)gridDim.x * blockDim.x) {
        int b = (int)(idx / per);
        long rem = idx - (long)b * per;
        int r = (int)(rem / Cc);
        int j = (int)(rem - (long)r * Cc);
        out[(long)b * per + (long)j * R + r] = in[idx];
    }
}

// Per-query GEMMs: offsets = tanh(q @ offW^T + offB)*R ; wl = q @ wW^T + wB
template <int NT>
__global__ void qgemm_k(const float* __restrict__ query,
                        const float* __restrict__ offT,  // [256][256] (j, r)
                        const float* __restrict__ offB,
                        const float* __restrict__ wT,    // [256][128] (j, r)
                        const float* __restrict__ wB,
                        float* __restrict__ offsets,     // [N][256]
                        float* __restrict__ wl,          // [N][128]
                        int N) {
    __shared__ float q[NT][CCH];
    int n0 = blockIdx.x * NT;
    int tid = threadIdx.x;
    for (int t = 0; t < NT; t++) {
        int n = n0 + t;
        q[t][tid] = (n < N) ? query[(long)n * CCH + tid] : 0.f;
    }
    __syncthreads();

    // offset rows: r = tid (0..255)
    {
        float acc[NT];
        float b = offB[tid];
#pragma unroll
        for (int t = 0; t < NT; t++) acc[t] = b;
        for (int j = 0; j < CCH; j++) {
            float wv = offT[j * CCH + tid];
#pragma unroll
            for (int t = 0; t < NT; t++) acc[t] = fmaf(q[t][j], wv, acc[t]);
        }
        for (int t = 0; t < NT; t++) {
            int n = n0 + t;
            if (n < N) offsets[(long)n * CCH + tid] = tanhf(acc[t]) * RADIUS_F;
        }
    }
    // attention-logit rows: r = tid (0..127), threads 128..255 idle (wave-uniform)
    if (tid < 128) {
        float acc[NT];
        float b = wB[tid];
#pragma unroll
        for (int t = 0; t < NT; t++) acc[t] = b;
        for (int j = 0; j < CCH; j++) {
            float wv = wT[j * 128 + tid];
#pragma unroll
            for (int t = 0; t < NT; t++) acc[t] = fmaf(q[t][j], wv, acc[t]);
        }
        for (int t = 0; t < NT; t++) {
            int n = n0 + t;
            if (n < N) wl[(long)n * 128 + tid] = acc[t];
        }
    }
}

// Per-query sampling + masked softmax + camera fusion.
// feat_t: [CAMS][HH][WW][CCH] (pixel-major -> coalesced channel reads)
// Block layout: 256 threads = 4 waves. Lane-group g = tid&63 owns channels
// [4g, 4g+3] (float4). Wave s = tid>>6 processes visible (cam,pip) pairs
// e = s, s+4, s+8, ... from a compacted list (wave-uniform branches).
__global__ void __launch_bounds__(256) sample_fuse_k(
        const float* __restrict__ feat_t,
        const float* __restrict__ refp,   // [CAMS][N][PIP][2]
        const int* __restrict__ bev,      // [CAMS][N][PIP] (0/1)
        const float* __restrict__ offsets,// [N][256]
        const float* __restrict__ wl,     // [N][128]
        float* __restrict__ fused,        // [N][256]
        int N) {
    int n = blockIdx.x;
    int tid = threadIdx.x;
    int s = tid >> 6;   // wave id
    int g = tid & 63;   // channel group (4 channels)
    int h = g >> 3;     // head

    __shared__ float ref_s[CAMS * PIP * 2];    // 48
    __shared__ int mask_s[CAMS * PIP];         // 24
    __shared__ float wl_s[HEADS * KK];         // 128
    __shared__ float off_s[CCH];               // 256
    __shared__ float w_s[CAMS * HEADS * KK];   // 768
    __shared__ int list_s[CAMS * PIP];         // compacted visible pairs
    __shared__ int cnt_s[2];                   // {num pairs, num visible cams}
    __shared__ float partial[4][64][4];

    if (tid < CAMS * PIP * 2) {
        int cam = tid >> 3, rem = tid & 7;
        ref_s[tid] = refp[((long)cam * N + n) * 8 + rem];
    }
    if (tid < CAMS * PIP) {
        int cam = tid >> 2, pip = tid & 3;
        mask_s[tid] = bev[((long)cam * N + n) * 4 + pip];
    }
    if (tid < 128) wl_s[tid] = wl[(long)n * 128 + tid];
    off_s[tid] = offsets[(long)n * CCH + tid];
    __syncthreads();

    // masked softmax per (cam, head): 48 threads each do one row of K=16
    if (tid < CAMS * HEADS) {
        int cam = tid >> 3, hh = tid & 7;
        float mmax = -1e30f;
        int any = 0;
#pragma unroll
        for (int k = 0; k < KK; k++) {
            if (mask_s[cam * PIP + (k >> 2)]) {
                float l = wl_s[hh * KK + k];
                mmax = fmaxf(mmax, l);
                any = 1;
            }
        }
        float e[KK];
        float ssum = 0.f;
#pragma unroll
        for (int k = 0; k < KK; k++) {
            float v = 0.f;
            if (mask_s[cam * PIP + (k >> 2)]) {
                v = expf(wl_s[hh * KK + k] - mmax);
                ssum += v;
            }
            e[k] = v;
        }
        float inv = any ? 1.f / ssum : 0.f;
#pragma unroll
        for (int k = 0; k < KK; k++) w_s[(cam * HEADS + hh) * KK + k] = e[k] * inv;
    }
    if (tid == 0) {
        int m = 0, ccount = 0;
        for (int cam = 0; cam < CAMS; cam++) {
            int hv = mask_s[cam * 4] | mask_s[cam * 4 + 1] |
                     mask_s[cam * 4 + 2] | mask_s[cam * 4 + 3];
            if (hv) ccount++;
        }
        for (int pr = 0; pr < CAMS * PIP; pr++)
            if (mask_s[pr]) list_s[m++] = pr;
        cnt_s[0] = m;
        cnt_s[1] = ccount;
    }
    __syncthreads();

    int m = cnt_s[0];
    float ax = 0.f, ay = 0.f, az = 0.f, aw = 0.f;
    for (int e = s; e < m; e += 4) {   // wave-uniform
        int pair = list_s[e];
        int cam = pair >> 2, pip = pair & 3;
        const float* fcam = feat_t + ((long)cam * HH * WW) * CCH + (g << 2);
        float rx = ref_s[pair * 2 + 0];
        float ry = ref_s[pair * 2 + 1];
#pragma unroll
        for (int p = 0; p < PP; p++) {
            int k = pip * PP + p;
            float wgt = w_s[(cam * HEADS + h) * KK + k];
            float lx = rx + off_s[((h * PIP + pip) * PP + p) * 2 + 0];
            float ly = ry + off_s[((h * PIP + pip) * PP + p) * 2 + 1];
            float x = fmaf(lx, (float)WW, -0.5f);
            float y = fmaf(ly, (float)HH, -0.5f);
            float x0f = floorf(x), y0f = floorf(y);
            float fx = x - x0f, fy = y - y0f;
            int ix = (int)x0f, iy = (int)y0f;
            int ix0 = min(max(ix, 0), WW - 1);
            int ix1 = min(max(ix + 1, 0), WW - 1);
            int iy0 = min(max(iy, 0), HH - 1);
            int iy1 = min(max(iy + 1, 0), HH - 1);
            // full two-sided validity on every corner (zeros padding)
            float wx0 = (1.f - fx) * (((ix >= 0) & (ix < WW)) ? 1.f : 0.f);
            float wx1 = fx * (((ix + 1 >= 0) & (ix + 1 < WW)) ? 1.f : 0.f);
            float wy0 = (1.f - fy) * (((iy >= 0) & (iy < HH)) ? 1.f : 0.f);
            float wy1 = fy * (((iy + 1 >= 0) & (iy + 1 < HH)) ? 1.f : 0.f);
            const float4 f00 = *(const float4*)(fcam + (long)(iy0 * WW + ix0) * CCH);
            const float4 f01 = *(const float4*)(fcam + (long)(iy0 * WW + ix1) * CCH);
            const float4 f10 = *(const float4*)(fcam + (long)(iy1 * WW + ix0) * CCH);
            const float4 f11 = *(const float4*)(fcam + (long)(iy1 * WW + ix1) * CCH);
            float a00 = wgt * wy0 * wx0;
            float a01 = wgt * wy0 * wx1;
            float a10 = wgt * wy1 * wx0;
            float a11 = wgt * wy1 * wx1;
            ax = fmaf(a00, f00.x, ax); ay = fmaf(a00, f00.y, ay);
            az = fmaf(a00, f00.z, az); aw = fmaf(a00, f00.w, aw);
            ax = fmaf(a01, f01.x, ax); ay = fmaf(a01, f01.y, ay);
            az = fmaf(a01, f01.z, az); aw = fmaf(a01, f01.w, aw);
            ax = fmaf(a10, f10.x, ax); ay = fmaf(a10, f10.y, ay);
            az = fmaf(a10, f10.z, az); aw = fmaf(a10, f10.w, aw);
            ax = fmaf(a11, f11.x, ax); ay = fmaf(a11, f11.y, ay);
            az = fmaf(a11, f11.z, az); aw = fmaf(a11, f11.w, aw);
        }
    }
    partial[s][g][0] = ax;
    partial[s][g][1] = ay;
    partial[s][g][2] = az;
    partial[s][g][3] = aw;
    __syncthreads();

    if (tid < 64) {
        int ccount = cnt_s[1];
        float inv = 1.f / (float)max(ccount, 1);
        float4 r;
        r.x = (partial[0][tid][0] + partial[1][tid][0] + partial[2][tid][0] + partial[3][tid][0]) * inv;
        r.y = (partial[0][tid][1] + partial[1][tid][1] + partial[2][tid][1] + partial[3][tid][1]) * inv;
        r.z = (partial[0][tid][2] + partial[1][tid][2] + partial[2][tid][2] + partial[3][tid][2]) * inv;
        r.w = (partial[0][tid][3] + partial[1][tid][3] + partial[2][tid][3] + partial[3][tid][3]) * inv;
        *(float4*)(fused + (long)n * CCH + (tid << 2)) = r;
    }
}

// out = fused @ out_w^T + out_b
template <int NT>
__global__ void outproj_k(const float* __restrict__ fused,
                          const float* __restrict__ outT,  // [256][256] (j, r)
                          const float* __restrict__ outB,
                          float* __restrict__ out, int N) {
    __shared__ float f[NT][CCH];
    int n0 = blockIdx.x * NT;
    int tid = threadIdx.x;
    for (int t = 0; t < NT; t++) {
        int n = n0 + t;
        f[t][tid] = (n < N) ? fused[(long)n * CCH + tid] : 0.f;
    }
    __syncthreads();
    float acc[NT];
    float b = outB[tid];
#pragma unroll
    for (int t = 0; t < NT; t++) acc[t] = b;
    for (int j = 0; j < CCH; j++) {
        float wv = outT[j * CCH + tid];
#pragma unroll
        for (int t = 0; t < NT; t++) acc[t] = fmaf(f[t][j], wv, acc[t]);
    }
    for (int t = 0; t < NT; t++) {
        int n = n0 + t;
        if (n < N) out[(long)n * CCH + tid] = acc[t];
    }
}

extern "C" void kernel_launch(void* const* d_in, const int* in_sizes, int n_in,
                              void* d_out, int out_size, void* d_ws, size_t ws_size,
                              hipStream_t stream) {
    const float* query    = (const float*)d_in[0];  // [1,N,256]
    const float* imfeat   = (const float*)d_in[1];  // [1,6,256,46,80]
    const float* refp     = (const float*)d_in[2];  // [1,6,N,4,2]
    const int*   bev      = (const int*)d_in[3];    // [1,6,N,4] bool->int32
    const float* offset_w = (const float*)d_in[4];  // [256,256]
    const float* offset_b = (const float*)d_in[5];  // [256]
    const float* weight_w = (const float*)d_in[6];  // [128,256]
    const float* weight_b = (const float*)d_in[7];  // [128]
    const float* out_w    = (const float*)d_in[8];  // [256,256]
    const float* out_b    = (const float*)d_in[9];  // [256]
    float* out = (float*)d_out;

    int N = in_sizes[0] / CCH;  // 2500

    // workspace partition (floats)
    float* ws = (float*)d_ws;
    float* feat_t = ws;                                        // 6*46*80*256
    float* offT   = feat_t + (size_t)CAMS * HH * WW * CCH;     // 256*256
    float* wTw    = offT + (size_t)CCH * CCH;                  // 256*128
    float* outT   = wTw + (size_t)128 * CCH;                   // 256*256
    float* offs   = outT + (size_t)CCH * CCH;                  // N*256
    float* wl     = offs + (size_t)N * CCH;                    // N*128
    float* fusedb = wl + (size_t)N * 128;                      // N*256

    // transposes
    batched_transpose_k<<<2048, 256, 0, stream>>>(imfeat, feat_t, CAMS, CCH, HH * WW);
    batched_transpose_k<<<256, 256, 0, stream>>>(offset_w, offT, 1, CCH, CCH);
    batched_transpose_k<<<128, 256, 0, stream>>>(weight_w, wTw, 1, 128, CCH);
    batched_transpose_k<<<256, 256, 0, stream>>>(out_w, outT, 1, CCH, CCH);

    qgemm_k<8><<<(N + 7) / 8, 256, 0, stream>>>(query, offT, offset_b, wTw, weight_b,
                                                offs, wl, N);
    sample_fuse_k<<<N, 256, 0, stream>>>(feat_t, refp, bev, offs, wl, fusedb, N);
    outproj_k<8><<<(N + 7) / 8, 256, 0, stream>>>(fusedb, outT, out_b, out, N);
}

// Round 4
// 149.027 us; speedup vs baseline: 2.1519x; 1.3469x over previous
//
#include <hip/hip_runtime.h>
#include <math.h>

#define CAMS 6
#define CCH 256
#define HH 46
#define WW 80
#define NPIX (HH * WW)
#define HEADS 8
#define PIP 4
#define PP 4
#define KK 16
#define RADIUS_F 0.12f

// LDS-tiled transpose of image feats: in [6][256][3680] -> out [6][3680][256]
__global__ void __launch_bounds__(256) feat_transpose_k(const float* __restrict__ in,
                                                        float* __restrict__ out) {
    __shared__ float tile[64][65];
    int cam = blockIdx.z;
    int r0 = blockIdx.y * 64;   // channel block
    int p0 = blockIdx.x * 64;   // pixel block
    int tj = threadIdx.x & 63;
    int ti = threadIdx.x >> 6;
    const float* src = in + ((long)cam * CCH + r0) * NPIX + p0;
#pragma unroll
    for (int k = 0; k < 64; k += 4) {
        if (p0 + tj < NPIX) tile[ti + k][tj] = src[(long)(ti + k) * NPIX + tj];
    }
    __syncthreads();
    float* dst = out + ((long)cam * NPIX + p0) * CCH + r0;
#pragma unroll
    for (int k = 0; k < 64; k += 4) {
        if (p0 + ti + k < NPIX) dst[(long)(ti + k) * CCH + tj] = tile[tj][ti + k];
    }
}

// Fused tiled transpose of the three weight matrices.
// offset_w [256][256]->offT [256][256] : tiles 0..15
// weight_w [128][256]->wT   [256][128] : tiles 16..23
// out_w    [256][256]->outT [256][256] : tiles 24..39
__global__ void __launch_bounds__(256) wtrans_k(const float* __restrict__ offw,
                                                const float* __restrict__ ww,
                                                const float* __restrict__ outw,
                                                float* __restrict__ offT,
                                                float* __restrict__ wT,
                                                float* __restrict__ outT) {
    __shared__ float tile[64][65];
    int b = blockIdx.x;
    const float* src;
    float* dst;
    int R, C, tr, tc;
    if (b < 16)      { src = offw; dst = offT; R = 256; C = 256; tr = b >> 2;        tc = b & 3; }
    else if (b < 24) { src = ww;   dst = wT;   R = 128; C = 256; tr = (b - 16) >> 2; tc = (b - 16) & 3; }
    else             { src = outw; dst = outT; R = 256; C = 256; tr = (b - 24) >> 2; tc = (b - 24) & 3; }
    int tj = threadIdx.x & 63;
    int ti = threadIdx.x >> 6;
#pragma unroll
    for (int k = 0; k < 64; k += 4)
        tile[ti + k][tj] = src[(long)(tr * 64 + ti + k) * C + tc * 64 + tj];
    __syncthreads();
#pragma unroll
    for (int k = 0; k < 64; k += 4)
        dst[(long)(tc * 64 + ti + k) * R + tr * 64 + tj] = tile[tj][ti + k];
}

// Per-query GEMMs: offsets = tanh(q @ offW^T + offB)*R ; wl = q @ wW^T + wB
template <int NT>
__global__ void qgemm_k(const float* __restrict__ query,
                        const float* __restrict__ offT,  // [256][256] (j, r)
                        const float* __restrict__ offB,
                        const float* __restrict__ wT,    // [256][128] (j, r)
                        const float* __restrict__ wB,
                        float* __restrict__ offsets,     // [N][256]
                        float* __restrict__ wl,          // [N][128]
                        int N) {
    __shared__ float q[NT][CCH];
    int n0 = blockIdx.x * NT;
    int tid = threadIdx.x;
    for (int t = 0; t < NT; t++) {
        int n = n0 + t;
        q[t][tid] = (n < N) ? query[(long)n * CCH + tid] : 0.f;
    }
    __syncthreads();

    {
        float acc[NT];
        float b = offB[tid];
#pragma unroll
        for (int t = 0; t < NT; t++) acc[t] = b;
        for (int j = 0; j < CCH; j++) {
            float wv = offT[j * CCH + tid];
#pragma unroll
            for (int t = 0; t < NT; t++) acc[t] = fmaf(q[t][j], wv, acc[t]);
        }
        for (int t = 0; t < NT; t++) {
            int n = n0 + t;
            if (n < N) offsets[(long)n * CCH + tid] = tanhf(acc[t]) * RADIUS_F;
        }
    }
    if (tid < 128) {
        float acc[NT];
        float b = wB[tid];
#pragma unroll
        for (int t = 0; t < NT; t++) acc[t] = b;
        for (int j = 0; j < CCH; j++) {
            float wv = wT[j * 128 + tid];
#pragma unroll
            for (int t = 0; t < NT; t++) acc[t] = fmaf(q[t][j], wv, acc[t]);
        }
        for (int t = 0; t < NT; t++) {
            int n = n0 + t;
            if (n < N) wl[(long)n * 128 + tid] = acc[t];
        }
    }
}

__device__ __forceinline__ void do_pair(int pair, int h, int g,
                                        const float* __restrict__ feat_t,
                                        const float* __restrict__ ref_s,
                                        const float* __restrict__ off_s,
                                        const float* __restrict__ w_s,
                                        float& ax, float& ay, float& az, float& aw) {
    int cam = pair >> 2, pip = pair & 3;
    const float* fcam = feat_t + ((long)cam * NPIX) * CCH + (g << 2);
    float rx = ref_s[pair * 2 + 0];
    float ry = ref_s[pair * 2 + 1];
#pragma unroll
    for (int p = 0; p < PP; p++) {
        int k = pip * PP + p;
        float wgt = w_s[(cam * HEADS + h) * KK + k];
        float lx = rx + off_s[((h * PIP + pip) * PP + p) * 2 + 0];
        float ly = ry + off_s[((h * PIP + pip) * PP + p) * 2 + 1];
        float x = fmaf(lx, (float)WW, -0.5f);
        float y = fmaf(ly, (float)HH, -0.5f);
        float x0f = floorf(x), y0f = floorf(y);
        float fx = x - x0f, fy = y - y0f;
        int ix = (int)x0f, iy = (int)y0f;
        int ix0 = min(max(ix, 0), WW - 1);
        int ix1 = min(max(ix + 1, 0), WW - 1);
        int iy0 = min(max(iy, 0), HH - 1);
        int iy1 = min(max(iy + 1, 0), HH - 1);
        float wx0 = (1.f - fx) * (((ix >= 0) & (ix < WW)) ? 1.f : 0.f);
        float wx1 = fx * (((ix + 1 >= 0) & (ix + 1 < WW)) ? 1.f : 0.f);
        float wy0 = (1.f - fy) * (((iy >= 0) & (iy < HH)) ? 1.f : 0.f);
        float wy1 = fy * (((iy + 1 >= 0) & (iy + 1 < HH)) ? 1.f : 0.f);
        const float4 f00 = *(const float4*)(fcam + (long)(iy0 * WW + ix0) * CCH);
        const float4 f01 = *(const float4*)(fcam + (long)(iy0 * WW + ix1) * CCH);
        const float4 f10 = *(const float4*)(fcam + (long)(iy1 * WW + ix0) * CCH);
        const float4 f11 = *(const float4*)(fcam + (long)(iy1 * WW + ix1) * CCH);
        float a00 = wgt * wy0 * wx0;
        float a01 = wgt * wy0 * wx1;
        float a10 = wgt * wy1 * wx0;
        float a11 = wgt * wy1 * wx1;
        ax = fmaf(a00, f00.x, ax); ay = fmaf(a00, f00.y, ay);
        az = fmaf(a00, f00.z, az); aw = fmaf(a00, f00.w, aw);
        ax = fmaf(a01, f01.x, ax); ay = fmaf(a01, f01.y, ay);
        az = fmaf(a01, f01.z, az); aw = fmaf(a01, f01.w, aw);
        ax = fmaf(a10, f10.x, ax); ay = fmaf(a10, f10.y, ay);
        az = fmaf(a10, f10.z, az); aw = fmaf(a10, f10.w, aw);
        ax = fmaf(a11, f11.x, ax); ay = fmaf(a11, f11.y, ay);
        az = fmaf(a11, f11.z, az); aw = fmaf(a11, f11.w, aw);
    }
}

// Per-query sampling + masked softmax + camera fusion.
// feat_t: [CAMS][HH][WW][CCH] (pixel-major -> coalesced channel reads)
// 4 waves/block; lane-group g owns 4 channels; wave s takes pairs s, s+4, ...
// Two pairs per loop iteration for ILP; __launch_bounds__(256,4) gives the
// compiler a 128-VGPR budget to keep the float4 loads in flight.
__global__ void __launch_bounds__(256, 4) sample_fuse_k(
        const float* __restrict__ feat_t,
        const float* __restrict__ refp,   // [CAMS][N][PIP][2]
        const int* __restrict__ bev,      // [CAMS][N][PIP] (0/1)
        const float* __restrict__ offsets,// [N][256]
        const float* __restrict__ wl,     // [N][128]
        float* __restrict__ fused,        // [N][256]
        int N) {
    int n = blockIdx.x;
    int tid = threadIdx.x;
    int s = tid >> 6;   // wave id
    int g = tid & 63;   // channel group (4 channels)
    int h = g >> 3;     // head

    __shared__ float ref_s[CAMS * PIP * 2];
    __shared__ int mask_s[CAMS * PIP];
    __shared__ float wl_s[HEADS * KK];
    __shared__ float off_s[CCH];
    __shared__ float w_s[CAMS * HEADS * KK];
    __shared__ int list_s[CAMS * PIP];
    __shared__ int cnt_s[2];
    __shared__ float partial[4][64][4];

    if (tid < CAMS * PIP * 2) {
        int cam = tid >> 3, rem = tid & 7;
        ref_s[tid] = refp[((long)cam * N + n) * 8 + rem];
    }
    if (tid < CAMS * PIP) {
        int cam = tid >> 2, pip = tid & 3;
        mask_s[tid] = bev[((long)cam * N + n) * 4 + pip];
    }
    if (tid < 128) wl_s[tid] = wl[(long)n * 128 + tid];
    off_s[tid] = offsets[(long)n * CCH + tid];
    __syncthreads();

    if (tid < CAMS * HEADS) {
        int cam = tid >> 3, hh = tid & 7;
        float mmax = -1e30f;
        int any = 0;
#pragma unroll
        for (int k = 0; k < KK; k++) {
            if (mask_s[cam * PIP + (k >> 2)]) {
                float l = wl_s[hh * KK + k];
                mmax = fmaxf(mmax, l);
                any = 1;
            }
        }
        float e[KK];
        float ssum = 0.f;
#pragma unroll
        for (int k = 0; k < KK; k++) {
            float v = 0.f;
            if (mask_s[cam * PIP + (k >> 2)]) {
                v = expf(wl_s[hh * KK + k] - mmax);
                ssum += v;
            }
            e[k] = v;
        }
        float inv = any ? 1.f / ssum : 0.f;
#pragma unroll
        for (int k = 0; k < KK; k++) w_s[(cam * HEADS + hh) * KK + k] = e[k] * inv;
    }
    if (tid == 0) {
        int m = 0, ccount = 0;
        for (int cam = 0; cam < CAMS; cam++) {
            int hv = mask_s[cam * 4] | mask_s[cam * 4 + 1] |
                     mask_s[cam * 4 + 2] | mask_s[cam * 4 + 3];
            if (hv) ccount++;
        }
        for (int pr = 0; pr < CAMS * PIP; pr++)
            if (mask_s[pr]) list_s[m++] = pr;
        cnt_s[0] = m;
        cnt_s[1] = ccount;
    }
    __syncthreads();

    int m = cnt_s[0];
    float ax = 0.f, ay = 0.f, az = 0.f, aw = 0.f;
    for (int e = s; e < m; e += 8) {   // wave-uniform, 2 pairs/iter
        int pa = list_s[e];
        do_pair(pa, h, g, feat_t, ref_s, off_s, w_s, ax, ay, az, aw);
        if (e + 4 < m) {
            int pb = list_s[e + 4];
            do_pair(pb, h, g, feat_t, ref_s, off_s, w_s, ax, ay, az, aw);
        }
    }
    partial[s][g][0] = ax;
    partial[s][g][1] = ay;
    partial[s][g][2] = az;
    partial[s][g][3] = aw;
    __syncthreads();

    if (tid < 64) {
        int ccount = cnt_s[1];
        float inv = 1.f / (float)max(ccount, 1);
        float4 r;
        r.x = (partial[0][tid][0] + partial[1][tid][0] + partial[2][tid][0] + partial[3][tid][0]) * inv;
        r.y = (partial[0][tid][1] + partial[1][tid][1] + partial[2][tid][1] + partial[3][tid][1]) * inv;
        r.z = (partial[0][tid][2] + partial[1][tid][2] + partial[2][tid][2] + partial[3][tid][2]) * inv;
        r.w = (partial[0][tid][3] + partial[1][tid][3] + partial[2][tid][3] + partial[3][tid][3]) * inv;
        *(float4*)(fused + (long)n * CCH + (tid << 2)) = r;
    }
}

// out = fused @ out_w^T + out_b
template <int NT>
__global__ void outproj_k(const float* __restrict__ fused,
                          const float* __restrict__ outT,  // [256][256] (j, r)
                          const float* __restrict__ outB,
                          float* __restrict__ out, int N) {
    __shared__ float f[NT][CCH];
    int n0 = blockIdx.x * NT;
    int tid = threadIdx.x;
    for (int t = 0; t < NT; t++) {
        int n = n0 + t;
        f[t][tid] = (n < N) ? fused[(long)n * CCH + tid] : 0.f;
    }
    __syncthreads();
    float acc[NT];
    float b = outB[tid];
#pragma unroll
    for (int t = 0; t < NT; t++) acc[t] = b;
    for (int j = 0; j < CCH; j++) {
        float wv = outT[j * CCH + tid];
#pragma unroll
        for (int t = 0; t < NT; t++) acc[t] = fmaf(f[t][j], wv, acc[t]);
    }
    for (int t = 0; t < NT; t++) {
        int n = n0 + t;
        if (n < N) out[(long)n * CCH + tid] = acc[t];
    }
}

extern "C" void kernel_launch(void* const* d_in, const int* in_sizes, int n_in,
                              void* d_out, int out_size, void* d_ws, size_t ws_size,
                              hipStream_t stream) {
    const float* query    = (const float*)d_in[0];
    const float* imfeat   = (const float*)d_in[1];
    const float* refp     = (const float*)d_in[2];
    const int*   bev      = (const int*)d_in[3];
    const float* offset_w = (const float*)d_in[4];
    const float* offset_b = (const float*)d_in[5];
    const float* weight_w = (const float*)d_in[6];
    const float* weight_b = (const float*)d_in[7];
    const float* out_w    = (const float*)d_in[8];
    const float* out_b    = (const float*)d_in[9];
    float* out = (float*)d_out;

    int N = in_sizes[0] / CCH;  // 2500

    float* ws = (float*)d_ws;
    float* feat_t = ws;                                        // 6*3680*256
    float* offT   = feat_t + (size_t)CAMS * NPIX * CCH;        // 256*256
    float* wTw    = offT + (size_t)CCH * CCH;                  // 256*128
    float* outT   = wTw + (size_t)128 * CCH;                   // 256*256
    float* offs   = outT + (size_t)CCH * CCH;                  // N*256
    float* wl     = offs + (size_t)N * CCH;                    // N*128
    float* fusedb = wl + (size_t)N * 128;                      // N*256

    feat_transpose_k<<<dim3((NPIX + 63) / 64, CCH / 64, CAMS), 256, 0, stream>>>(imfeat, feat_t);
    wtrans_k<<<40, 256, 0, stream>>>(offset_w, weight_w, out_w, offT, wTw, outT);

    qgemm_k<8><<<(N + 7) / 8, 256, 0, stream>>>(query, offT, offset_b, wTw, weight_b,
                                                offs, wl, N);
    sample_fuse_k<<<N, 256, 0, stream>>>(feat_t, refp, bev, offs, wl, fusedb, N);
    outproj_k<8><<<(N + 7) / 8, 256, 0, stream>>>(fusedb, outT, out_b, out, N);
}

// Round 5
// 128.200 us; speedup vs baseline: 2.5015x; 1.1625x over previous
//
#include <hip/hip_runtime.h>
#include <math.h>

#define CAMS 6
#define CCH 256
#define HH 46
#define WW 80
#define NPIX (HH * WW)
#define HEADS 8
#define PIP 4
#define PP 4
#define KK 16
#define RADIUS_F 0.12f

__device__ __forceinline__ unsigned short f2bf(float f) {
    unsigned int x = __float_as_uint(f);
    unsigned int r = (x + 0x7FFFu + ((x >> 16) & 1u)) >> 16;  // RNE
    return (unsigned short)r;
}
__device__ __forceinline__ float bf2f(unsigned short u) {
    return __uint_as_float(((unsigned int)u) << 16);
}

// LDS-tiled transpose+convert: in [6][256][3680] f32 -> out [6][3680][256] bf16
__global__ void __launch_bounds__(256) feat_transpose_k(const float* __restrict__ in,
                                                        unsigned short* __restrict__ out) {
    __shared__ float tile[64][65];
    int cam = blockIdx.z;
    int r0 = blockIdx.y * 64;   // channel block
    int p0 = blockIdx.x * 64;   // pixel block
    int tj = threadIdx.x & 63;
    int ti = threadIdx.x >> 6;
    const float* src = in + ((long)cam * CCH + r0) * NPIX + p0;
#pragma unroll
    for (int k = 0; k < 64; k += 4) {
        if (p0 + tj < NPIX) tile[ti + k][tj] = src[(long)(ti + k) * NPIX + tj];
    }
    __syncthreads();
    unsigned short* dst = out + ((long)cam * NPIX + p0) * CCH + r0;
#pragma unroll
    for (int k = 0; k < 64; k += 4) {
        if (p0 + ti + k < NPIX) dst[(long)(ti + k) * CCH + tj] = f2bf(tile[tj][ti + k]);
    }
}

// Fused tiled transpose of the three weight matrices (f32).
__global__ void __launch_bounds__(256) wtrans_k(const float* __restrict__ offw,
                                                const float* __restrict__ ww,
                                                const float* __restrict__ outw,
                                                float* __restrict__ offT,
                                                float* __restrict__ wT,
                                                float* __restrict__ outT) {
    __shared__ float tile[64][65];
    int b = blockIdx.x;
    const float* src;
    float* dst;
    int R, C, tr, tc;
    if (b < 16)      { src = offw; dst = offT; R = 256; C = 256; tr = b >> 2;        tc = b & 3; }
    else if (b < 24) { src = ww;   dst = wT;   R = 128; C = 256; tr = (b - 16) >> 2; tc = (b - 16) & 3; }
    else             { src = outw; dst = outT; R = 256; C = 256; tr = (b - 24) >> 2; tc = (b - 24) & 3; }
    int tj = threadIdx.x & 63;
    int ti = threadIdx.x >> 6;
#pragma unroll
    for (int k = 0; k < 64; k += 4)
        tile[ti + k][tj] = src[(long)(tr * 64 + ti + k) * C + tc * 64 + tj];
    __syncthreads();
#pragma unroll
    for (int k = 0; k < 64; k += 4)
        dst[(long)(tc * 64 + ti + k) * R + tr * 64 + tj] = tile[tj][ti + k];
}

// Per-query GEMMs: offsets = tanh(q @ offW^T + offB)*R ; wl = q @ wW^T + wB
template <int NT>
__global__ void qgemm_k(const float* __restrict__ query,
                        const float* __restrict__ offT,  // [256][256] (j, r)
                        const float* __restrict__ offB,
                        const float* __restrict__ wT,    // [256][128] (j, r)
                        const float* __restrict__ wB,
                        float* __restrict__ offsets,     // [N][256]
                        float* __restrict__ wl,          // [N][128]
                        int N) {
    __shared__ float q[NT][CCH];
    int n0 = blockIdx.x * NT;
    int tid = threadIdx.x;
    for (int t = 0; t < NT; t++) {
        int n = n0 + t;
        q[t][tid] = (n < N) ? query[(long)n * CCH + tid] : 0.f;
    }
    __syncthreads();

    {
        float acc[NT];
        float b = offB[tid];
#pragma unroll
        for (int t = 0; t < NT; t++) acc[t] = b;
        for (int j = 0; j < CCH; j++) {
            float wv = offT[j * CCH + tid];
#pragma unroll
            for (int t = 0; t < NT; t++) acc[t] = fmaf(q[t][j], wv, acc[t]);
        }
        for (int t = 0; t < NT; t++) {
            int n = n0 + t;
            if (n < N) offsets[(long)n * CCH + tid] = tanhf(acc[t]) * RADIUS_F;
        }
    }
    if (tid < 128) {
        float acc[NT];
        float b = wB[tid];
#pragma unroll
        for (int t = 0; t < NT; t++) acc[t] = b;
        for (int j = 0; j < CCH; j++) {
            float wv = wT[j * 128 + tid];
#pragma unroll
            for (int t = 0; t < NT; t++) acc[t] = fmaf(q[t][j], wv, acc[t]);
        }
        for (int t = 0; t < NT; t++) {
            int n = n0 + t;
            if (n < N) wl[(long)n * 128 + tid] = acc[t];
        }
    }
}

__device__ __forceinline__ void do_pair(int pair, int h, int g,
                                        const unsigned short* __restrict__ feat_t,
                                        const float* __restrict__ ref_s,
                                        const float* __restrict__ off_s,
                                        const float* __restrict__ w_s,
                                        float& ax, float& ay, float& az, float& aw) {
    int cam = pair >> 2, pip = pair & 3;
    // lane-group g covers channels [4g, 4g+4): ushort4 at element offset 4g
    const ushort4* fcam = (const ushort4*)(feat_t + (long)cam * NPIX * CCH) + g;
    float rx = ref_s[pair * 2 + 0];
    float ry = ref_s[pair * 2 + 1];
#pragma unroll
    for (int p = 0; p < PP; p++) {
        int k = pip * PP + p;
        float wgt = w_s[(cam * HEADS + h) * KK + k];
        float lx = rx + off_s[((h * PIP + pip) * PP + p) * 2 + 0];
        float ly = ry + off_s[((h * PIP + pip) * PP + p) * 2 + 1];
        float x = fmaf(lx, (float)WW, -0.5f);
        float y = fmaf(ly, (float)HH, -0.5f);
        float x0f = floorf(x), y0f = floorf(y);
        float fx = x - x0f, fy = y - y0f;
        int ix = (int)x0f, iy = (int)y0f;
        int ix0 = min(max(ix, 0), WW - 1);
        int ix1 = min(max(ix + 1, 0), WW - 1);
        int iy0 = min(max(iy, 0), HH - 1);
        int iy1 = min(max(iy + 1, 0), HH - 1);
        float wx0 = (1.f - fx) * (((ix >= 0) & (ix < WW)) ? 1.f : 0.f);
        float wx1 = fx * (((ix + 1 >= 0) & (ix + 1 < WW)) ? 1.f : 0.f);
        float wy0 = (1.f - fy) * (((iy >= 0) & (iy < HH)) ? 1.f : 0.f);
        float wy1 = fy * (((iy + 1 >= 0) & (iy + 1 < HH)) ? 1.f : 0.f);
        const ushort4 u00 = fcam[(long)(iy0 * WW + ix0) * (CCH / 4)];
        const ushort4 u01 = fcam[(long)(iy0 * WW + ix1) * (CCH / 4)];
        const ushort4 u10 = fcam[(long)(iy1 * WW + ix0) * (CCH / 4)];
        const ushort4 u11 = fcam[(long)(iy1 * WW + ix1) * (CCH / 4)];
        float a00 = wgt * wy0 * wx0;
        float a01 = wgt * wy0 * wx1;
        float a10 = wgt * wy1 * wx0;
        float a11 = wgt * wy1 * wx1;
        ax = fmaf(a00, bf2f(u00.x), ax); ay = fmaf(a00, bf2f(u00.y), ay);
        az = fmaf(a00, bf2f(u00.z), az); aw = fmaf(a00, bf2f(u00.w), aw);
        ax = fmaf(a01, bf2f(u01.x), ax); ay = fmaf(a01, bf2f(u01.y), ay);
        az = fmaf(a01, bf2f(u01.z), az); aw = fmaf(a01, bf2f(u01.w), aw);
        ax = fmaf(a10, bf2f(u10.x), ax); ay = fmaf(a10, bf2f(u10.y), ay);
        az = fmaf(a10, bf2f(u10.z), az); aw = fmaf(a10, bf2f(u10.w), aw);
        ax = fmaf(a11, bf2f(u11.x), ax); ay = fmaf(a11, bf2f(u11.y), ay);
        az = fmaf(a11, bf2f(u11.z), az); aw = fmaf(a11, bf2f(u11.w), aw);
    }
}

// Per-query sampling + masked softmax + camera fusion (bf16 feats).
__global__ void __launch_bounds__(256, 4) sample_fuse_k(
        const unsigned short* __restrict__ feat_t,
        const float* __restrict__ refp,   // [CAMS][N][PIP][2]
        const int* __restrict__ bev,      // [CAMS][N][PIP] (0/1)
        const float* __restrict__ offsets,// [N][256]
        const float* __restrict__ wl,     // [N][128]
        float* __restrict__ fused,        // [N][256]
        int N) {
    int n = blockIdx.x;
    int tid = threadIdx.x;
    int s = tid >> 6;   // wave id
    int g = tid & 63;   // channel group (4 channels)
    int h = g >> 3;     // head

    __shared__ float ref_s[CAMS * PIP * 2];
    __shared__ int mask_s[CAMS * PIP];
    __shared__ float wl_s[HEADS * KK];
    __shared__ float off_s[CCH];
    __shared__ float w_s[CAMS * HEADS * KK];
    __shared__ int list_s[CAMS * PIP];
    __shared__ int cnt_s[2];
    __shared__ float partial[4][64][4];

    if (tid < CAMS * PIP * 2) {
        int cam = tid >> 3, rem = tid & 7;
        ref_s[tid] = refp[((long)cam * N + n) * 8 + rem];
    }
    if (tid < CAMS * PIP) {
        int cam = tid >> 2, pip = tid & 3;
        mask_s[tid] = bev[((long)cam * N + n) * 4 + pip];
    }
    if (tid < 128) wl_s[tid] = wl[(long)n * 128 + tid];
    off_s[tid] = offsets[(long)n * CCH + tid];
    __syncthreads();

    if (tid < CAMS * HEADS) {
        int cam = tid >> 3, hh = tid & 7;
        float mmax = -1e30f;
        int any = 0;
#pragma unroll
        for (int k = 0; k < KK; k++) {
            if (mask_s[cam * PIP + (k >> 2)]) {
                float l = wl_s[hh * KK + k];
                mmax = fmaxf(mmax, l);
                any = 1;
            }
        }
        float e[KK];
        float ssum = 0.f;
#pragma unroll
        for (int k = 0; k < KK; k++) {
            float v = 0.f;
            if (mask_s[cam * PIP + (k >> 2)]) {
                v = expf(wl_s[hh * KK + k] - mmax);
                ssum += v;
            }
            e[k] = v;
        }
        float inv = any ? 1.f / ssum : 0.f;
#pragma unroll
        for (int k = 0; k < KK; k++) w_s[(cam * HEADS + hh) * KK + k] = e[k] * inv;
    }
    if (tid == 0) {
        int m = 0, ccount = 0;
        for (int cam = 0; cam < CAMS; cam++) {
            int hv = mask_s[cam * 4] | mask_s[cam * 4 + 1] |
                     mask_s[cam * 4 + 2] | mask_s[cam * 4 + 3];
            if (hv) ccount++;
        }
        for (int pr = 0; pr < CAMS * PIP; pr++)
            if (mask_s[pr]) list_s[m++] = pr;
        cnt_s[0] = m;
        cnt_s[1] = ccount;
    }
    __syncthreads();

    int m = cnt_s[0];
    float ax = 0.f, ay = 0.f, az = 0.f, aw = 0.f;
    for (int e = s; e < m; e += 8) {   // wave-uniform, 2 pairs/iter
        int pa = list_s[e];
        do_pair(pa, h, g, feat_t, ref_s, off_s, w_s, ax, ay, az, aw);
        if (e + 4 < m) {
            int pb = list_s[e + 4];
            do_pair(pb, h, g, feat_t, ref_s, off_s, w_s, ax, ay, az, aw);
        }
    }
    partial[s][g][0] = ax;
    partial[s][g][1] = ay;
    partial[s][g][2] = az;
    partial[s][g][3] = aw;
    __syncthreads();

    if (tid < 64) {
        int ccount = cnt_s[1];
        float inv = 1.f / (float)max(ccount, 1);
        float4 r;
        r.x = (partial[0][tid][0] + partial[1][tid][0] + partial[2][tid][0] + partial[3][tid][0]) * inv;
        r.y = (partial[0][tid][1] + partial[1][tid][1] + partial[2][tid][1] + partial[3][tid][1]) * inv;
        r.z = (partial[0][tid][2] + partial[1][tid][2] + partial[2][tid][2] + partial[3][tid][2]) * inv;
        r.w = (partial[0][tid][3] + partial[1][tid][3] + partial[2][tid][3] + partial[3][tid][3]) * inv;
        *(float4*)(fused + (long)n * CCH + (tid << 2)) = r;
    }
}

// out = fused @ out_w^T + out_b
template <int NT>
__global__ void outproj_k(const float* __restrict__ fused,
                          const float* __restrict__ outT,  // [256][256] (j, r)
                          const float* __restrict__ outB,
                          float* __restrict__ out, int N) {
    __shared__ float f[NT][CCH];
    int n0 = blockIdx.x * NT;
    int tid = threadIdx.x;
    for (int t = 0; t < NT; t++) {
        int n = n0 + t;
        f[t][tid] = (n < N) ? fused[(long)n * CCH + tid] : 0.f;
    }
    __syncthreads();
    float acc[NT];
    float b = outB[tid];
#pragma unroll
    for (int t = 0; t < NT; t++) acc[t] = b;
    for (int j = 0; j < CCH; j++) {
        float wv = outT[j * CCH + tid];
#pragma unroll
        for (int t = 0; t < NT; t++) acc[t] = fmaf(f[t][j], wv, acc[t]);
    }
    for (int t = 0; t < NT; t++) {
        int n = n0 + t;
        if (n < N) out[(long)n * CCH + tid] = acc[t];
    }
}

extern "C" void kernel_launch(void* const* d_in, const int* in_sizes, int n_in,
                              void* d_out, int out_size, void* d_ws, size_t ws_size,
                              hipStream_t stream) {
    const float* query    = (const float*)d_in[0];
    const float* imfeat   = (const float*)d_in[1];
    const float* refp     = (const float*)d_in[2];
    const int*   bev      = (const int*)d_in[3];
    const float* offset_w = (const float*)d_in[4];
    const float* offset_b = (const float*)d_in[5];
    const float* weight_w = (const float*)d_in[6];
    const float* weight_b = (const float*)d_in[7];
    const float* out_w    = (const float*)d_in[8];
    const float* out_b    = (const float*)d_in[9];
    float* out = (float*)d_out;

    int N = in_sizes[0] / CCH;  // 2500

    float* ws = (float*)d_ws;
    unsigned short* feat_t = (unsigned short*)ws;              // 6*3680*256 bf16
    float* offT   = ws + (size_t)CAMS * NPIX * CCH / 2;        // 256*256
    float* wTw    = offT + (size_t)CCH * CCH;                  // 256*128
    float* outT   = wTw + (size_t)128 * CCH;                   // 256*256
    float* offs   = outT + (size_t)CCH * CCH;                  // N*256
    float* wl     = offs + (size_t)N * CCH;                    // N*128
    float* fusedb = wl + (size_t)N * 128;                      // N*256

    feat_transpose_k<<<dim3((NPIX + 63) / 64, CCH / 64, CAMS), 256, 0, stream>>>(imfeat, feat_t);
    wtrans_k<<<40, 256, 0, stream>>>(offset_w, weight_w, out_w, offT, wTw, outT);

    qgemm_k<8><<<(N + 7) / 8, 256, 0, stream>>>(query, offT, offset_b, wTw, weight_b,
                                                offs, wl, N);
    sample_fuse_k<<<N, 256, 0, stream>>>(feat_t, refp, bev, offs, wl, fusedb, N);
    outproj_k<8><<<(N + 7) / 8, 256, 0, stream>>>(fusedb, outT, out_b, out, N);
}

// Round 6
// 111.477 us; speedup vs baseline: 2.8768x; 1.1500x over previous
//
#include <hip/hip_runtime.h>
#include <math.h>

#define CAMS 6
#define CCH 256
#define HH 46
#define WW 80
#define NPIX (HH * WW)
#define HEADS 8
#define PIP 4
#define PP 4
#define KK 16
#define RADIUS_F 0.12f

__device__ __forceinline__ unsigned short f2bf(float f) {
    unsigned int x = __float_as_uint(f);
    unsigned int r = (x + 0x7FFFu + ((x >> 16) & 1u)) >> 16;  // RNE
    return (unsigned short)r;
}
__device__ __forceinline__ float bf2f(unsigned short u) {
    return __uint_as_float(((unsigned int)u) << 16);
}

// LDS-tiled transpose+convert: in [6][256][3680] f32 -> out [6][3680][256] bf16
__global__ void __launch_bounds__(256) feat_transpose_k(const float* __restrict__ in,
                                                        unsigned short* __restrict__ out) {
    __shared__ float tile[64][65];
    int cam = blockIdx.z;
    int r0 = blockIdx.y * 64;   // channel block
    int p0 = blockIdx.x * 64;   // pixel block
    int tj = threadIdx.x & 63;
    int ti = threadIdx.x >> 6;
    const float* src = in + ((long)cam * CCH + r0) * NPIX + p0;
#pragma unroll
    for (int k = 0; k < 64; k += 4) {
        if (p0 + tj < NPIX) tile[ti + k][tj] = src[(long)(ti + k) * NPIX + tj];
    }
    __syncthreads();
    unsigned short* dst = out + ((long)cam * NPIX + p0) * CCH + r0;
#pragma unroll
    for (int k = 0; k < 64; k += 4) {
        if (p0 + ti + k < NPIX) dst[(long)(ti + k) * CCH + tj] = f2bf(tile[tj][ti + k]);
    }
}

// Fused tiled transpose of the three weight matrices (f32).
__global__ void __launch_bounds__(256) wtrans_k(const float* __restrict__ offw,
                                                const float* __restrict__ ww,
                                                const float* __restrict__ outw,
                                                float* __restrict__ offT,
                                                float* __restrict__ wT,
                                                float* __restrict__ outT) {
    __shared__ float tile[64][65];
    int b = blockIdx.x;
    const float* src;
    float* dst;
    int R, C, tr, tc;
    if (b < 16)      { src = offw; dst = offT; R = 256; C = 256; tr = b >> 2;        tc = b & 3; }
    else if (b < 24) { src = ww;   dst = wT;   R = 128; C = 256; tr = (b - 16) >> 2; tc = (b - 16) & 3; }
    else             { src = outw; dst = outT; R = 256; C = 256; tr = (b - 24) >> 2; tc = (b - 24) & 3; }
    int tj = threadIdx.x & 63;
    int ti = threadIdx.x >> 6;
#pragma unroll
    for (int k = 0; k < 64; k += 4)
        tile[ti + k][tj] = src[(long)(tr * 64 + ti + k) * C + tc * 64 + tj];
    __syncthreads();
#pragma unroll
    for (int k = 0; k < 64; k += 4)
        dst[(long)(tc * 64 + ti + k) * R + tr * 64 + tj] = tile[tj][ti + k];
}

// Per-query GEMMs: offsets = tanh(q @ offW^T + offB)*R ; wl = q @ wW^T + wB
template <int NT>
__global__ void qgemm_k(const float* __restrict__ query,
                        const float* __restrict__ offT,  // [256][256] (j, r)
                        const float* __restrict__ offB,
                        const float* __restrict__ wT,    // [256][128] (j, r)
                        const float* __restrict__ wB,
                        float* __restrict__ offsets,     // [N][256]
                        float* __restrict__ wl,          // [N][128]
                        int N) {
    __shared__ float q[NT][CCH];
    int n0 = blockIdx.x * NT;
    int tid = threadIdx.x;
    for (int t = 0; t < NT; t++) {
        int n = n0 + t;
        q[t][tid] = (n < N) ? query[(long)n * CCH + tid] : 0.f;
    }
    __syncthreads();

    {
        float acc[NT];
        float b = offB[tid];
#pragma unroll
        for (int t = 0; t < NT; t++) acc[t] = b;
        for (int j = 0; j < CCH; j++) {
            float wv = offT[j * CCH + tid];
#pragma unroll
            for (int t = 0; t < NT; t++) acc[t] = fmaf(q[t][j], wv, acc[t]);
        }
        for (int t = 0; t < NT; t++) {
            int n = n0 + t;
            if (n < N) offsets[(long)n * CCH + tid] = tanhf(acc[t]) * RADIUS_F;
        }
    }
    if (tid < 128) {
        float acc[NT];
        float b = wB[tid];
#pragma unroll
        for (int t = 0; t < NT; t++) acc[t] = b;
        for (int j = 0; j < CCH; j++) {
            float wv = wT[j * 128 + tid];
#pragma unroll
            for (int t = 0; t < NT; t++) acc[t] = fmaf(q[t][j], wv, acc[t]);
        }
        for (int t = 0; t < NT; t++) {
            int n = n0 + t;
            if (n < N) wl[(long)n * 128 + tid] = acc[t];
        }
    }
}

// Per-(cam,query) sampling. One wave per task; tasks cam-major, partitioned
// into 8 contiguous ranges pinned to XCDs via blockIdx%8 (round-robin
// dispatch). Each XCD touches <=2 cams (<=3.7 MB bf16) -> L2-resident.
// No LDS, no barriers: offsets/logits/weights live in registers per lane.
__global__ void __launch_bounds__(256, 4) sample_cam_k(
        const unsigned short* __restrict__ feat_t,  // [CAMS][NPIX][CCH] bf16
        const float* __restrict__ refp,             // [CAMS][N][PIP][2]
        const int* __restrict__ bev,                // [CAMS][N][PIP]
        const float* __restrict__ offsets,          // [N][256] = [N][h][pip][p][2]
        const float* __restrict__ wl,               // [N][128] = [N][h][16]
        float* __restrict__ cam_out,                // [CAMS][N][256]
        int N, int per_xcd) {
    int xcd = blockIdx.x & 7;
    int local = (blockIdx.x >> 3) * 4 + (threadIdx.x >> 6);
    if (local >= per_xcd) return;                 // wave-uniform
    long task = (long)xcd * per_xcd + local;
    if (task >= (long)CAMS * N) return;
    int cam = (int)(task / N);
    int n = (int)(task - (long)cam * N);

    int l = threadIdx.x & 63;   // lane: owns channels 4l..4l+3
    int h = l >> 3;             // head

    const int* bv = bev + ((long)cam * N + n) * 4;
    int m0 = bv[0], m1 = bv[1], m2 = bv[2], m3 = bv[3];
    float* outp = cam_out + ((long)cam * N + n) * CCH + (l << 2);
    if (!(m0 | m1 | m2 | m3)) {
        *(float4*)outp = make_float4(0.f, 0.f, 0.f, 0.f);
        return;
    }

    const float* rp = refp + ((long)cam * N + n) * 8;
    const float4* offn = (const float4*)(offsets + (long)n * CCH + (h << 5));
    const float4* wln = (const float4*)(wl + (long)n * 128 + (h << 4));

    // logits for visible pips
    float4 wl0, wl1, wl2, wl3;
    float mmax = -1e30f;
    if (m0) { wl0 = wln[0]; mmax = fmaxf(mmax, fmaxf(fmaxf(wl0.x, wl0.y), fmaxf(wl0.z, wl0.w))); }
    if (m1) { wl1 = wln[1]; mmax = fmaxf(mmax, fmaxf(fmaxf(wl1.x, wl1.y), fmaxf(wl1.z, wl1.w))); }
    if (m2) { wl2 = wln[2]; mmax = fmaxf(mmax, fmaxf(fmaxf(wl2.x, wl2.y), fmaxf(wl2.z, wl2.w))); }
    if (m3) { wl3 = wln[3]; mmax = fmaxf(mmax, fmaxf(fmaxf(wl3.x, wl3.y), fmaxf(wl3.z, wl3.w))); }

    float w_[KK];
#pragma unroll
    for (int k = 0; k < KK; k++) w_[k] = 0.f;
    float ssum = 0.f;
    if (m0) {
        w_[0] = __expf(wl0.x - mmax); w_[1] = __expf(wl0.y - mmax);
        w_[2] = __expf(wl0.z - mmax); w_[3] = __expf(wl0.w - mmax);
        ssum += w_[0] + w_[1] + w_[2] + w_[3];
    }
    if (m1) {
        w_[4] = __expf(wl1.x - mmax); w_[5] = __expf(wl1.y - mmax);
        w_[6] = __expf(wl1.z - mmax); w_[7] = __expf(wl1.w - mmax);
        ssum += w_[4] + w_[5] + w_[6] + w_[7];
    }
    if (m2) {
        w_[8] = __expf(wl2.x - mmax); w_[9] = __expf(wl2.y - mmax);
        w_[10] = __expf(wl2.z - mmax); w_[11] = __expf(wl2.w - mmax);
        ssum += w_[8] + w_[9] + w_[10] + w_[11];
    }
    if (m3) {
        w_[12] = __expf(wl3.x - mmax); w_[13] = __expf(wl3.y - mmax);
        w_[14] = __expf(wl3.z - mmax); w_[15] = __expf(wl3.w - mmax);
        ssum += w_[12] + w_[13] + w_[14] + w_[15];
    }
    float inv = 1.f / ssum;   // folded into the final scale

    const ushort4* fcam = (const ushort4*)(feat_t + (long)cam * NPIX * CCH) + l;
    float ax = 0.f, ay = 0.f, az = 0.f, aw = 0.f;

#pragma unroll
    for (int pip = 0; pip < PIP; pip++) {
        int vis = (pip == 0) ? m0 : (pip == 1) ? m1 : (pip == 2) ? m2 : m3;
        if (!vis) continue;   // wave-uniform
        float rx = rp[pip * 2 + 0];
        float ry = rp[pip * 2 + 1];
        float4 oa = offn[pip * 2];       // [p0.x p0.y p1.x p1.y]
        float4 ob = offn[pip * 2 + 1];   // [p2.x p2.y p3.x p3.y]
        float px[PP] = {oa.x, oa.z, ob.x, ob.z};
        float py[PP] = {oa.y, oa.w, ob.y, ob.w};
#pragma unroll
        for (int p = 0; p < PP; p++) {
            float wgt = w_[pip * PP + p];
            float x = fmaf(rx + px[p], (float)WW, -0.5f);
            float y = fmaf(ry + py[p], (float)HH, -0.5f);
            float x0f = floorf(x), y0f = floorf(y);
            float fx = x - x0f, fy = y - y0f;
            int ix = (int)x0f, iy = (int)y0f;
            int ix0 = min(max(ix, 0), WW - 1);
            int ix1 = min(max(ix + 1, 0), WW - 1);
            int iy0 = min(max(iy, 0), HH - 1);
            int iy1 = min(max(iy + 1, 0), HH - 1);
            float wx0 = (1.f - fx) * (((ix >= 0) & (ix < WW)) ? 1.f : 0.f);
            float wx1 = fx * (((ix + 1 >= 0) & (ix + 1 < WW)) ? 1.f : 0.f);
            float wy0 = (1.f - fy) * (((iy >= 0) & (iy < HH)) ? 1.f : 0.f);
            float wy1 = fy * (((iy + 1 >= 0) & (iy + 1 < HH)) ? 1.f : 0.f);
            const ushort4 u00 = fcam[(iy0 * WW + ix0) * (CCH / 4)];
            const ushort4 u01 = fcam[(iy0 * WW + ix1) * (CCH / 4)];
            const ushort4 u10 = fcam[(iy1 * WW + ix0) * (CCH / 4)];
            const ushort4 u11 = fcam[(iy1 * WW + ix1) * (CCH / 4)];
            float a00 = wgt * wy0 * wx0;
            float a01 = wgt * wy0 * wx1;
            float a10 = wgt * wy1 * wx0;
            float a11 = wgt * wy1 * wx1;
            ax = fmaf(a00, bf2f(u00.x), ax); ay = fmaf(a00, bf2f(u00.y), ay);
            az = fmaf(a00, bf2f(u00.z), az); aw = fmaf(a00, bf2f(u00.w), aw);
            ax = fmaf(a01, bf2f(u01.x), ax); ay = fmaf(a01, bf2f(u01.y), ay);
            az = fmaf(a01, bf2f(u01.z), az); aw = fmaf(a01, bf2f(u01.w), aw);
            ax = fmaf(a10, bf2f(u10.x), ax); ay = fmaf(a10, bf2f(u10.y), ay);
            az = fmaf(a10, bf2f(u10.z), az); aw = fmaf(a10, bf2f(u10.w), aw);
            ax = fmaf(a11, bf2f(u11.x), ax); ay = fmaf(a11, bf2f(u11.y), ay);
            az = fmaf(a11, bf2f(u11.z), az); aw = fmaf(a11, bf2f(u11.w), aw);
        }
    }
    *(float4*)outp = make_float4(ax * inv, ay * inv, az * inv, aw * inv);
}

// out[n] = ((sum_cam cam_out[cam][n]) / count[n]) @ out_w^T + out_b
template <int NT>
__global__ void outproj_fuse_k(const float* __restrict__ cam_out,
                               const int* __restrict__ bev,
                               const float* __restrict__ outT,  // [256][256] (j, r)
                               const float* __restrict__ outB,
                               float* __restrict__ out, int N) {
    __shared__ float f[NT][CCH];
    __shared__ float inv_s[NT];
    int n0 = blockIdx.x * NT;
    int tid = threadIdx.x;
    for (int t = 0; t < NT; t++) {
        int n = n0 + t;
        float sum = 0.f;
        if (n < N) {
#pragma unroll
            for (int cam = 0; cam < CAMS; cam++)
                sum += cam_out[((long)cam * N + n) * CCH + tid];
        }
        f[t][tid] = sum;
    }
    if (tid < NT) {
        int n = n0 + tid;
        int cnt = 0;
        if (n < N) {
#pragma unroll
            for (int cam = 0; cam < CAMS; cam++) {
                const int* bv = bev + ((long)cam * N + n) * 4;
                cnt += (bv[0] | bv[1] | bv[2] | bv[3]) ? 1 : 0;
            }
        }
        inv_s[tid] = 1.f / (float)max(cnt, 1);
    }
    __syncthreads();
    float acc[NT];
#pragma unroll
    for (int t = 0; t < NT; t++) acc[t] = 0.f;
    for (int j = 0; j < CCH; j++) {
        float wv = outT[j * CCH + tid];
#pragma unroll
        for (int t = 0; t < NT; t++) acc[t] = fmaf(f[t][j], wv, acc[t]);
    }
    float b = outB[tid];
    for (int t = 0; t < NT; t++) {
        int n = n0 + t;
        if (n < N) out[(long)n * CCH + tid] = fmaf(acc[t], inv_s[t], b);
    }
}

extern "C" void kernel_launch(void* const* d_in, const int* in_sizes, int n_in,
                              void* d_out, int out_size, void* d_ws, size_t ws_size,
                              hipStream_t stream) {
    const float* query    = (const float*)d_in[0];
    const float* imfeat   = (const float*)d_in[1];
    const float* refp     = (const float*)d_in[2];
    const int*   bev      = (const int*)d_in[3];
    const float* offset_w = (const float*)d_in[4];
    const float* offset_b = (const float*)d_in[5];
    const float* weight_w = (const float*)d_in[6];
    const float* weight_b = (const float*)d_in[7];
    const float* out_w    = (const float*)d_in[8];
    const float* out_b    = (const float*)d_in[9];
    float* out = (float*)d_out;

    int N = in_sizes[0] / CCH;  // 2500

    float* ws = (float*)d_ws;
    unsigned short* feat_t = (unsigned short*)ws;              // 6*3680*256 bf16
    float* offT   = ws + (size_t)CAMS * NPIX * CCH / 2;        // 256*256
    float* wTw    = offT + (size_t)CCH * CCH;                  // 256*128
    float* outT   = wTw + (size_t)128 * CCH;                   // 256*256
    float* offs   = outT + (size_t)CCH * CCH;                  // N*256
    float* wl     = offs + (size_t)N * CCH;                    // N*128
    float* camob  = wl + (size_t)N * 128;                      // CAMS*N*256

    feat_transpose_k<<<dim3((NPIX + 63) / 64, CCH / 64, CAMS), 256, 0, stream>>>(imfeat, feat_t);
    wtrans_k<<<40, 256, 0, stream>>>(offset_w, weight_w, out_w, offT, wTw, outT);

    qgemm_k<8><<<(N + 7) / 8, 256, 0, stream>>>(query, offT, offset_b, wTw, weight_b,
                                                offs, wl, N);

    int T = CAMS * N;                       // 15000 tasks
    int per_xcd = (T + 7) / 8;              // 1875
    int blocks = 8 * ((per_xcd + 3) / 4);   // 4 tasks (waves) per block
    sample_cam_k<<<blocks, 256, 0, stream>>>(feat_t, refp, bev, offs, wl, camob,
                                             N, per_xcd);

    outproj_fuse_k<8><<<(N + 7) / 8, 256, 0, stream>>>(camob, bev, outT, out_b, out, N);
}